// Round 4
// baseline (1898.723 us; speedup 1.0000x reference)
//
#include <hip/hip_runtime.h>
#include <cstdint>

// ---------------------------------------------------------------------------
// MaskedDeepRNN fused: 2-layer masked LSTM, B=64 T=512 D_IN=256 H=512 G=2048.
// Single persistent kernel, 512 WGs (2/CU):
//   blocks   0..255 = layer 0, blocks 256..511 = layer 1.
// Islands of 32 WGs per 8-batch slice (blockIdx&7 -> XCD). Layer-1 lags
// layer-0 by >=1 step through an 8-slot L3 ring.
//
// Controlled experiment this round (H3): in-register cell math (R1) + the
// PROVEN sync structure (baseline/R3): wave0-only poll, 64B-stride flags,
// post-poll barrier, 2 WGs/CU for cross-WG latency hiding. vs baseline this
// removes the glp LDS partial-reduction round trip, the serial tid<128 gate
// section, and one barrier (4 -> 3 per step).
//   - R1 lesson: all-wave polling -> L2 poll storm (-700us). Reverted.
//   - R3 lesson: 1 WG/CU loses co-residency overlap (-200us). Reverted.
// ---------------------------------------------------------------------------

typedef _Float16 f16;
typedef _Float16 half8 __attribute__((ext_vector_type(8)));
typedef _Float16 half4v __attribute__((ext_vector_type(4)));
typedef float floatx4 __attribute__((ext_vector_type(4)));

#define B_ 64
#define T_ 512
#define DIN_ 256
#define H_ 512
#define G_ 2048

// workspace layout (bytes)
static const size_t OFF_FLAGS = 0;                              // 2 lay x 8 isl x 32 flags x 64B = 32 KB
static const size_t OFF_H0B   = 32768;                          // 8 isl x 8 slots x 8KB = 512 KB
static const size_t OFF_H1B   = OFF_H0B + 524288;               // 8 isl x 2 slots x 8KB = 128 KB
static const size_t OFF_WIH0  = OFF_H1B + 131072;
static const size_t OFF_WHH0  = OFF_WIH0 + (size_t)G_ * DIN_ * 2;
static const size_t OFF_WIH1  = OFF_WHH0 + (size_t)G_ * H_ * 2;
static const size_t OFF_WHH1  = OFF_WIH1 + (size_t)G_ * H_ * 2;
static const size_t OFF_B0    = OFF_WHH1 + (size_t)G_ * H_ * 2;
static const size_t OFF_B1    = OFF_B0 + 8192;
static const size_t ZERO_BYTES = OFF_WIH0;                      // flags + h rings

__device__ __forceinline__ uint32_t ald(const uint32_t* p) {
    return __hip_atomic_load(p, __ATOMIC_RELAXED, __HIP_MEMORY_SCOPE_AGENT);
}
__device__ __forceinline__ void ast(uint32_t* p, uint32_t v) {
    __hip_atomic_store(p, v, __ATOMIC_RELAXED, __HIP_MEMORY_SCOPE_AGENT);
}

// ---------------------------------------------------------------- prep ------
__global__ void k_maskw(const float* __restrict__ w, const float* __restrict__ m,
                        f16* __restrict__ o, int n4) {
    int i = blockIdx.x * 256 + threadIdx.x;
    if (i < n4) {
        const float4 wv = ((const float4*)w)[i];
        const float4 mv = ((const float4*)m)[i];
        half4v h = { (f16)(wv.x * mv.x), (f16)(wv.y * mv.y),
                     (f16)(wv.z * mv.z), (f16)(wv.w * mv.w) };
        ((half4v*)o)[i] = h;
    }
}

__global__ void k_bias(const float* __restrict__ a, const float* __restrict__ b,
                       float* __restrict__ o) {
    int i = blockIdx.x * 256 + threadIdx.x;
    if (i < G_) o[i] = a[i] + b[i];
}

// ------------------------------------------------------------ helpers -------
__device__ __forceinline__ void poll_flags(const uint32_t* ownF, uint32_t town,
                                           const uint32_t* crossF, uint32_t tcr,
                                           int lane) {
    // lanes 0..31 watch own-island flags, 32..63 the partner layer's island
    const uint32_t* p = (lane < 32) ? (ownF + (size_t)lane * 16)
                                    : (crossF + (size_t)(lane - 32) * 16);
    const uint32_t tgt = (lane < 32) ? town : tcr;
    while (true) {
        const uint32_t v = ald(p);
        if (__all((int)(v >= tgt))) break;
        __builtin_amdgcn_s_sleep(1);
    }
}

__device__ __forceinline__ float lstm_cell(float gi, float gf, float gg, float go,
                                           float& c) {
    const float i_ = 1.f / (1.f + __expf(-gi));
    const float f_ = 1.f / (1.f + __expf(-gf));
    const float gc = fminf(fmaxf(gg, -20.f), 20.f);
    const float e2 = __expf(2.f * gc);
    const float g_ = (e2 - 1.f) / (e2 + 1.f);
    const float o_ = 1.f / (1.f + __expf(-go));
    c = f_ * c + i_ * g_;
    const float cc  = fminf(fmaxf(c, -20.f), 20.f);
    const float e2c = __expf(2.f * cc);
    return o_ * (e2c - 1.f) / (e2c + 1.f);
}

// -------------------------------------------------------- fused kernel ------
__global__ __launch_bounds__(256, 2) void fused_rnn(
    const float* __restrict__ x,
    const f16* __restrict__ Wih0, const f16* __restrict__ Whh0,
    const float* __restrict__ bs0,
    const f16* __restrict__ Wih1, const f16* __restrict__ Whh1,
    const float* __restrict__ bs1,
    float* __restrict__ dout,
    uint32_t* __restrict__ h0b,      // [8 isl][8 slots][2048 dw] f16 pairs
    uint32_t* __restrict__ h1b,      // [8 isl][2 slots][2048 dw]
    uint32_t* __restrict__ flags)    // [2 lay][8 isl][32 x 16 dw]
{
    __shared__ f16 bl0[8][520];            // B-operand: own-layer h
    __shared__ f16 bl1[8][520];            // B-operand: x (L0) or h0 (L1)

    const int tid  = threadIdx.x;
    const int bid  = blockIdx.x;
    const int isl  = bid & 7;              // -> XCD under round-robin
    const int mem  = (bid >> 3) & 31;
    const int layer = bid >> 8;
    const int jb = mem * 16, b0 = isl * 8;
    const int wave = tid >> 6, lane = tid & 63, lm = lane & 15, quad = lane >> 4;
    const int hrow = lm < 8 ? lm : 7;      // cols 8..15 duplicate row 7 (discarded)
    const int jj = (wave << 2) + quad;     // this lane's j-jb in the cell phase

    uint32_t* ownF   = flags + (size_t)(layer * 8 + isl) * 512;
    uint32_t* crossF = flags + (size_t)((1 - layer) * 8 + isl) * 512;
    uint32_t* h0i = h0b + (size_t)isl * 8 * 2048;
    uint32_t* h1i = h1b + (size_t)isl * 2 * 2048;

    if (layer == 0) {
        // ---- persistent A fragments, gate-interleaved rows: m = jsub*4+gt
        half8 ah[16], ai[8];
        {
            const int row = (lm & 3) * 512 + jb + (wave << 2) + (lm >> 2);
            const f16* wr = Whh0 + (size_t)row * H_ + quad * 8;
            const f16* xr = Wih0 + (size_t)row * DIN_ + quad * 8;
#pragma unroll
            for (int kk = 0; kk < 16; ++kk) ah[kk] = *(const half8*)(wr + kk * 32);
#pragma unroll
            for (int kk = 0; kk < 8; ++kk)  ai[kk] = *(const half8*)(xr + kk * 32);
        }
        float bias[4];
#pragma unroll
        for (int g = 0; g < 4; ++g) bias[g] = bs0[g * 512 + jb + jj];
        float c = 0.f;
        // x[t] slice for this island: thread -> (batch=tid>>5, k0=(tid&31)*8)
        const float* xp = x + (size_t)(b0 + (tid >> 5)) * T_ * DIN_ + (tid & 31) * 8;
        float4 xa = *(const float4*)xp;            // x[0] preloaded
        float4 xb = *(const float4*)(xp + 4);

        for (int t = 0; t < T_; ++t) {
            // own peers done with step t-1; L1 done with step t-8 (ring safety)
            if (wave == 0)
                poll_flags(ownF, (uint32_t)t, crossF,
                           t >= 7 ? (uint32_t)(t - 7) : 0u, lane);
            __syncthreads();
            // ---- stage h0[t-1] (ring slot (t-1)&7) + x[t]; prefetch x[t+1]
            {
                const uint32_t* hb = h0i + (size_t)((t + 7) & 7) * 2048;
                uint32_t va[8];
#pragma unroll
                for (int i = 0; i < 8; ++i) va[i] = ald(hb + i * 256 + tid);
                half8 hx = { (f16)xa.x, (f16)xa.y, (f16)xa.z, (f16)xa.w,
                             (f16)xb.x, (f16)xb.y, (f16)xb.z, (f16)xb.w };
                *(half8*)&bl1[tid >> 5][(tid & 31) * 8] = hx;
                const size_t tn = (size_t)(t + 1 < T_ ? t + 1 : t) * DIN_;
                xa = *(const float4*)(xp + tn);    // L2/L3-hot
                xb = *(const float4*)(xp + tn + 4);
#pragma unroll
                for (int i = 0; i < 8; ++i) {
                    const int u = i * 256 + tid;
                    *(uint32_t*)&bl0[u >> 8][(u & 255) * 2] = va[i];
                }
            }
            __syncthreads();
            // ---- MFMA: full K per wave, 4 independent acc chains
            floatx4 acc[4] = {};
            {
                const f16* br0 = &bl0[hrow][quad * 8];
                const f16* br1 = &bl1[hrow][quad * 8];
#pragma unroll
                for (int kk = 0; kk < 16; ++kk)
                    acc[kk & 3] = __builtin_amdgcn_mfma_f32_16x16x32_f16(
                        ah[kk], *(const half8*)(br0 + kk * 32), acc[kk & 3], 0, 0, 0);
#pragma unroll
                for (int kk = 0; kk < 8; ++kk)
                    acc[kk & 3] = __builtin_amdgcn_mfma_f32_16x16x32_f16(
                        ai[kk], *(const half8*)(br1 + kk * 32), acc[kk & 3], 0, 0, 0);
            }
            const floatx4 av = (acc[0] + acc[1]) + (acc[2] + acc[3]);
            // ---- gate math fully in-register: lane = (batch=lm, j=jb+jj)
            const float hn = lstm_cell(av[0] + bias[0], av[1] + bias[1],
                                       av[2] + bias[2], av[3] + bias[3], c);
            const float ho = __shfl_xor(hn, 16);   // partner quad -> j+1
            if (!(quad & 1) && lm < 8) {
                union { f16 h[2]; uint32_t u; } pk;
                pk.h[0] = (f16)hn; pk.h[1] = (f16)ho;
                ast(h0i + (size_t)(t & 7) * 2048 + (lm * H_ + jb + jj) / 2, pk.u);
            }
            __syncthreads();                       // drains h stores (vmcnt 0)
            if (tid == 0) ast(ownF + mem * 16, (uint32_t)(t + 1));
        }
    } else {
        // ---- layer 1: Whh1 + Wih1, both K=512, gates = h1.Whh1 + h0.Wih1
        half8 ah[16], ai[16];
        {
            const int row = (lm & 3) * 512 + jb + (wave << 2) + (lm >> 2);
            const f16* wr = Whh1 + (size_t)row * H_ + quad * 8;
            const f16* xr = Wih1 + (size_t)row * H_ + quad * 8;
#pragma unroll
            for (int kk = 0; kk < 16; ++kk) {
                ah[kk] = *(const half8*)(wr + kk * 32);
                ai[kk] = *(const half8*)(xr + kk * 32);
            }
        }
        float bias[4];
#pragma unroll
        for (int g = 0; g < 4; ++g) bias[g] = bs1[g * 512 + jb + jj];
        float c = 0.f;

        for (int t = 0; t < T_; ++t) {
            // own peers done with step t-1; L0 has published h0[t] (flag t+1)
            if (wave == 0)
                poll_flags(ownF, (uint32_t)t, crossF, (uint32_t)(t + 1), lane);
            __syncthreads();
            // ---- stage h1[t-1] (parity) + h0[t] (ring slot t&7)
            {
                const uint32_t* hb = h1i + (size_t)((t + 1) & 1) * 2048;
                const uint32_t* gb = h0i + (size_t)(t & 7) * 2048;
                uint32_t va[8], vb[8];
#pragma unroll
                for (int i = 0; i < 8; ++i) va[i] = ald(hb + i * 256 + tid);
#pragma unroll
                for (int i = 0; i < 8; ++i) vb[i] = ald(gb + i * 256 + tid);
#pragma unroll
                for (int i = 0; i < 8; ++i) {
                    const int u = i * 256 + tid;
                    *(uint32_t*)&bl0[u >> 8][(u & 255) * 2] = va[i];
                    *(uint32_t*)&bl1[u >> 8][(u & 255) * 2] = vb[i];
                }
            }
            __syncthreads();
            // ---- MFMA: 4 independent acc chains
            floatx4 acc[4] = {};
            {
                const f16* br0 = &bl0[hrow][quad * 8];
                const f16* br1 = &bl1[hrow][quad * 8];
#pragma unroll
                for (int kk = 0; kk < 16; ++kk) {
                    acc[kk & 3] = __builtin_amdgcn_mfma_f32_16x16x32_f16(
                        ah[kk], *(const half8*)(br0 + kk * 32), acc[kk & 3], 0, 0, 0);
                    acc[kk & 3] = __builtin_amdgcn_mfma_f32_16x16x32_f16(
                        ai[kk], *(const half8*)(br1 + kk * 32), acc[kk & 3], 0, 0, 0);
                }
            }
            const floatx4 av = (acc[0] + acc[1]) + (acc[2] + acc[3]);
            const float hn = lstm_cell(av[0] + bias[0], av[1] + bias[1],
                                       av[2] + bias[2], av[3] + bias[3], c);
            const float ho = __shfl_xor(hn, 16);
            if (!(quad & 1) && lm < 8) {
                union { f16 h[2]; uint32_t u; } pk;
                pk.h[0] = (f16)hn; pk.h[1] = (f16)ho;
                ast(h1i + (size_t)(t & 1) * 2048 + (lm * H_ + jb + jj) / 2, pk.u);
            }
            if (t == T_ - 1 && lm < 8)
                dout[(size_t)(b0 + lm) * H_ + jb + jj] = hn;
            __syncthreads();                       // drains h stores (vmcnt 0)
            if (tid == 0) ast(ownF + mem * 16, (uint32_t)(t + 1));
        }
    }
}

// ------------------------------------------------------------ launcher ------
extern "C" void kernel_launch(void* const* d_in, const int* in_sizes, int n_in,
                              void* d_out, int out_size, void* d_ws, size_t ws_size,
                              hipStream_t stream) {
    const float* x    = (const float*)d_in[0];
    const float* Wih0 = (const float*)d_in[1];
    const float* Whh0 = (const float*)d_in[2];
    const float* bih0 = (const float*)d_in[3];
    const float* bhh0 = (const float*)d_in[4];
    const float* mih0 = (const float*)d_in[5];
    const float* mhh0 = (const float*)d_in[6];
    const float* Wih1 = (const float*)d_in[7];
    const float* Whh1 = (const float*)d_in[8];
    const float* bih1 = (const float*)d_in[9];
    const float* bhh1 = (const float*)d_in[10];
    const float* mih1 = (const float*)d_in[11];
    const float* mhh1 = (const float*)d_in[12];

    char* ws = (char*)d_ws;
    uint32_t* flags = (uint32_t*)(ws + OFF_FLAGS);
    uint32_t* h0b   = (uint32_t*)(ws + OFF_H0B);
    uint32_t* h1b   = (uint32_t*)(ws + OFF_H1B);
    f16*   wih0 = (f16*)(ws + OFF_WIH0);
    f16*   whh0 = (f16*)(ws + OFF_WHH0);
    f16*   wih1 = (f16*)(ws + OFF_WIH1);
    f16*   whh1 = (f16*)(ws + OFF_WHH1);
    float* bs0  = (float*)(ws + OFF_B0);
    float* bs1  = (float*)(ws + OFF_B1);
    float* out  = (float*)d_out;

    // zero flags + h rings (ws is re-poisoned before every timed call)
    hipMemsetAsync(ws, 0, ZERO_BYTES, stream);

    k_maskw<<<512,  256, 0, stream>>>(Wih0, mih0, wih0, G_ * DIN_ / 4);
    k_maskw<<<1024, 256, 0, stream>>>(Whh0, mhh0, whh0, G_ * H_ / 4);
    k_maskw<<<1024, 256, 0, stream>>>(Wih1, mih1, wih1, G_ * H_ / 4);
    k_maskw<<<1024, 256, 0, stream>>>(Whh1, mhh1, whh1, G_ * H_ / 4);
    k_bias<<<8, 256, 0, stream>>>(bih0, bhh0, bs0);
    k_bias<<<8, 256, 0, stream>>>(bih1, bhh1, bs1);

    fused_rnn<<<512, 256, 0, stream>>>(x, wih0, whh0, bs0, wih1, whh1, bs1,
                                       out, h0b, h1b, flags);

    (void)in_sizes; (void)n_in; (void)out_size; (void)ws_size;
}

// Round 5
// 1355.243 us; speedup vs baseline: 1.4010x; 1.4010x over previous
//
#include <hip/hip_runtime.h>
#include <cstdint>

// ---------------------------------------------------------------------------
// MaskedDeepRNN fused: 2-layer masked LSTM, B=64 T=512 D_IN=256 H=512 G=2048.
// Single persistent kernel, 512 WGs (2/CU):
//   blocks   0..255 = layer 0, blocks 256..511 = layer 1.
// Islands of 32 WGs per 8-batch slice (blockIdx&7 -> XCD). Layer-1 lags
// layer-0 through an 8-slot L3 ring.
//
// R5 = EXACT baseline structure (glp LDS reduction, serial tid<128 gate math,
// coalesced publish, wave0-only poll, 64B-stride flags, 4 barriers/step) +
// latency-overlap only:
//  * split-phase MFMA: stage the flag-independent B operand (x for L0,
//    prefetched h0[t] for L1) at loop top; issue the flag-guarded ring reads
//    after the poll barrier and run the ih-MFMAs while they are in flight;
//    then stage bl0 and run the hh-MFMAs. Barrier count unchanged (4).
//  * L1 prefetches h0[t+1] into registers one step early (cross target
//    min(t+2,512)), halving L1's critical-path ring reads (16 -> 8).
// Session ledger: all-wave poll -700us (R1/R2); 1 WG/CU -200us (R3);
// in-reg cell math + scattered publish -220us (R4). All reverted.
// ---------------------------------------------------------------------------

typedef _Float16 f16;
typedef _Float16 half8 __attribute__((ext_vector_type(8)));
typedef _Float16 half4v __attribute__((ext_vector_type(4)));
typedef float floatx4 __attribute__((ext_vector_type(4)));

#define B_ 64
#define T_ 512
#define DIN_ 256
#define H_ 512
#define G_ 2048

// workspace layout (bytes)
static const size_t OFF_FLAGS = 0;                              // 2 lay x 8 isl x 32 flags x 64B = 32 KB
static const size_t OFF_H0B   = 32768;                          // 8 isl x 8 slots x 8KB = 512 KB
static const size_t OFF_H1B   = OFF_H0B + 524288;               // 8 isl x 2 slots x 8KB = 128 KB
static const size_t OFF_WIH0  = OFF_H1B + 131072;
static const size_t OFF_WHH0  = OFF_WIH0 + (size_t)G_ * DIN_ * 2;
static const size_t OFF_WIH1  = OFF_WHH0 + (size_t)G_ * H_ * 2;
static const size_t OFF_WHH1  = OFF_WIH1 + (size_t)G_ * H_ * 2;
static const size_t OFF_B0    = OFF_WHH1 + (size_t)G_ * H_ * 2;
static const size_t OFF_B1    = OFF_B0 + 8192;
static const size_t ZERO_BYTES = OFF_WIH0;                      // flags + h rings

__device__ __forceinline__ uint32_t ald(const uint32_t* p) {
    return __hip_atomic_load(p, __ATOMIC_RELAXED, __HIP_MEMORY_SCOPE_AGENT);
}
__device__ __forceinline__ void ast(uint32_t* p, uint32_t v) {
    __hip_atomic_store(p, v, __ATOMIC_RELAXED, __HIP_MEMORY_SCOPE_AGENT);
}

// ---------------------------------------------------------------- prep ------
__global__ void k_maskw(const float* __restrict__ w, const float* __restrict__ m,
                        f16* __restrict__ o, int n4) {
    int i = blockIdx.x * 256 + threadIdx.x;
    if (i < n4) {
        const float4 wv = ((const float4*)w)[i];
        const float4 mv = ((const float4*)m)[i];
        half4v h = { (f16)(wv.x * mv.x), (f16)(wv.y * mv.y),
                     (f16)(wv.z * mv.z), (f16)(wv.w * mv.w) };
        ((half4v*)o)[i] = h;
    }
}

__global__ void k_bias(const float* __restrict__ a, const float* __restrict__ b,
                       float* __restrict__ o) {
    int i = blockIdx.x * 256 + threadIdx.x;
    if (i < G_) o[i] = a[i] + b[i];
}

// ------------------------------------------------------------ helpers -------
__device__ __forceinline__ void poll_flags(const uint32_t* ownF, uint32_t town,
                                           const uint32_t* crossF, uint32_t tcr,
                                           int lane) {
    // lanes 0..31 watch own-island flags, 32..63 the partner layer's island
    const uint32_t* p = (lane < 32) ? (ownF + (size_t)lane * 16)
                                    : (crossF + (size_t)(lane - 32) * 16);
    const uint32_t tgt = (lane < 32) ? town : tcr;
    while (true) {
        const uint32_t v = ald(p);
        if (__all((int)(v >= tgt))) break;
        __builtin_amdgcn_s_sleep(1);
    }
}

__device__ __forceinline__ float lstm_cell(float gi, float gf, float gg, float go,
                                           float& c) {
    const float i_ = 1.f / (1.f + __expf(-gi));
    const float f_ = 1.f / (1.f + __expf(-gf));
    const float gc = fminf(fmaxf(gg, -20.f), 20.f);
    const float e2 = __expf(2.f * gc);
    const float g_ = (e2 - 1.f) / (e2 + 1.f);
    const float o_ = 1.f / (1.f + __expf(-go));
    c = f_ * c + i_ * g_;
    const float cc  = fminf(fmaxf(c, -20.f), 20.f);
    const float e2c = __expf(2.f * cc);
    return o_ * (e2c - 1.f) / (e2c + 1.f);
}

// -------------------------------------------------------- fused kernel ------
__global__ __launch_bounds__(256, 2) void fused_rnn(
    const float* __restrict__ x,
    const f16* __restrict__ Wih0, const f16* __restrict__ Whh0,
    const float* __restrict__ bs0,
    const f16* __restrict__ Wih1, const f16* __restrict__ Whh1,
    const float* __restrict__ bs1,
    float* __restrict__ dout,
    uint32_t* __restrict__ h0b,      // [8 isl][8 slots][2048 dw] f16 pairs
    uint32_t* __restrict__ h1b,      // [8 isl][2 slots][2048 dw]
    uint32_t* __restrict__ flags)    // [2 lay][8 isl][32 x 16 dw]
{
    __shared__ f16 bl0[8][520];            // B-operand: own-layer h
    __shared__ f16 bl1[8][520];            // B-operand: x (L0) or h0 (L1)
    __shared__ float glp[4][4][16][9];     // [wave][gate][jj][b] partials (pad 9)

    const int tid  = threadIdx.x;
    const int bid  = blockIdx.x;
    const int isl  = bid & 7;              // -> XCD under round-robin
    const int mem  = (bid >> 3) & 31;
    const int layer = bid >> 8;
    const int jb = mem * 16, b0 = isl * 8;
    const int wave = tid >> 6, lane = tid & 63, lm = lane & 15, quad = lane >> 4;
    const int eb = tid >> 4, ejj = tid & 15;
    const int hrow = lm < 8 ? lm : 7;      // cols 8..15 duplicate row 7 (discarded)

    uint32_t* ownF   = flags + (size_t)(layer * 8 + isl) * 512;
    uint32_t* crossF = flags + (size_t)((1 - layer) * 8 + isl) * 512;
    uint32_t* h0i = h0b + (size_t)isl * 8 * 2048;
    uint32_t* h1i = h1b + (size_t)isl * 2 * 2048;

    if (layer == 0) {
        // ---- persistent A fragments: Whh0 (K=512 split over waves) + Wih0
        half8 ah[4][4], ai[4][2];
        {
            const int kb  = wave * 128 + quad * 8;
            const int kbx = wave * 64 + quad * 8;
#pragma unroll
            for (int gt = 0; gt < 4; ++gt) {
                const f16* wr = Whh0 + (size_t)(gt * 512 + jb + lm) * H_ + kb;
                const f16* xr = Wih0 + (size_t)(gt * 512 + jb + lm) * DIN_ + kbx;
#pragma unroll
                for (int kk = 0; kk < 4; ++kk) ah[gt][kk] = *(const half8*)(wr + kk * 32);
#pragma unroll
                for (int kk = 0; kk < 2; ++kk) ai[gt][kk] = *(const half8*)(xr + kk * 32);
            }
        }
        float bias[4];
#pragma unroll
        for (int g = 0; g < 4; ++g) bias[g] = bs0[g * 512 + jb + ejj];
        float c = 0.f;
        // x[t] slice for this island: thread -> (batch=tid>>5, k0=(tid&31)*8)
        const float* xp = x + (size_t)(b0 + (tid >> 5)) * T_ * DIN_ + (tid & 31) * 8;
        float4 xa = *(const float4*)xp;            // x[0] preloaded
        float4 xb = *(const float4*)(xp + 4);

        for (int t = 0; t < T_; ++t) {
            // ---- loop top: stage x[t] into bl1 (no flag dependency), then
            //      reload x[t+1]; wave0 polls while others finish bl1 writes
            {
                half8 hx = { (f16)xa.x, (f16)xa.y, (f16)xa.z, (f16)xa.w,
                             (f16)xb.x, (f16)xb.y, (f16)xb.z, (f16)xb.w };
                *(half8*)&bl1[tid >> 5][(tid & 31) * 8] = hx;
                const size_t tn = (size_t)(t + 1 < T_ ? t + 1 : t) * DIN_;
                xa = *(const float4*)(xp + tn);    // lands during this step
                xb = *(const float4*)(xp + tn + 4);
            }
            // own peers done with step t-1; L1 done with step t-8 (ring safety)
            if (wave == 0)
                poll_flags(ownF, (uint32_t)t, crossF,
                           t >= 7 ? (uint32_t)(t - 7) : 0u, lane);
            __syncthreads();                       // barA: bl1 ready + poll done
            // ---- issue h0[t-1] ring reads (slot (t-1)&7), overlap with x-MFMAs
            uint32_t va[8];
            {
                const uint32_t* hb = h0i + (size_t)((t + 7) & 7) * 2048;
#pragma unroll
                for (int i = 0; i < 8; ++i) va[i] = ald(hb + i * 256 + tid);
            }
            floatx4 acc[4] = {};
            {
                const f16* br1 = &bl1[hrow][wave * 64 + quad * 8];
#pragma unroll
                for (int kk = 0; kk < 2; ++kk) {
                    const half8 bv = *(const half8*)(br1 + kk * 32);
#pragma unroll
                    for (int gt = 0; gt < 4; ++gt)
                        acc[gt] = __builtin_amdgcn_mfma_f32_16x16x32_f16(
                            ai[gt][kk], bv, acc[gt], 0, 0, 0);
                }
            }
            __builtin_amdgcn_sched_barrier(0);     // keep bl0 writes (vmcnt wait) after x-MFMAs
            // ---- stage h0[t-1] into bl0 (waits on va loads)
#pragma unroll
            for (int i = 0; i < 8; ++i) {
                const int u = i * 256 + tid;
                *(uint32_t*)&bl0[u >> 8][(u & 255) * 2] = va[i];
            }
            __syncthreads();                       // barB: bl0 ready
            {
                const f16* br0 = &bl0[hrow][wave * 128 + quad * 8];
#pragma unroll
                for (int kk = 0; kk < 4; ++kk) {
                    const half8 bv = *(const half8*)(br0 + kk * 32);
#pragma unroll
                    for (int gt = 0; gt < 4; ++gt)
                        acc[gt] = __builtin_amdgcn_mfma_f32_16x16x32_f16(
                            ah[gt][kk], bv, acc[gt], 0, 0, 0);
                }
            }
            if (lm < 8)
#pragma unroll
                for (int gt = 0; gt < 4; ++gt)
#pragma unroll
                    for (int r = 0; r < 4; ++r)
                        glp[wave][gt][quad * 4 + r][lm] = acc[gt][r];
            __syncthreads();                       // barC: glp ready
            // ---- gate math + coalesced publish into ring slot t&7
            if (tid < 128) {
                float gi = bias[0], gf = bias[1], gg = bias[2], go = bias[3];
#pragma unroll
                for (int w = 0; w < 4; ++w) {
                    gi += glp[w][0][ejj][eb]; gf += glp[w][1][ejj][eb];
                    gg += glp[w][2][ejj][eb]; go += glp[w][3][ejj][eb];
                }
                const float hn = lstm_cell(gi, gf, gg, go, c);
                const float ho = __shfl_xor(hn, 1);
                if (!(ejj & 1)) {
                    union { f16 h[2]; uint32_t u; } pk;
                    pk.h[0] = (f16)hn; pk.h[1] = (f16)ho;
                    ast(h0i + (size_t)(t & 7) * 2048 + (eb * H_ + jb + ejj) / 2, pk.u);
                }
            }
            __syncthreads();                       // barD: drains h stores
            if (tid == 0) ast(ownF + mem * 16, (uint32_t)(t + 1));
        }
    } else {
        // ---- layer 1: Whh1 + Wih1, both K=512, gates = h1.Whh1 + h0.Wih1
        half8 ah[4][4], ai[4][4];
        {
            const int kb = wave * 128 + quad * 8;
#pragma unroll
            for (int gt = 0; gt < 4; ++gt) {
                const f16* wr = Whh1 + (size_t)(gt * 512 + jb + lm) * H_ + kb;
                const f16* xr = Wih1 + (size_t)(gt * 512 + jb + lm) * H_ + kb;
#pragma unroll
                for (int kk = 0; kk < 4; ++kk) {
                    ah[gt][kk] = *(const half8*)(wr + kk * 32);
                    ai[gt][kk] = *(const half8*)(xr + kk * 32);
                }
            }
        }
        float bias[4];
#pragma unroll
        for (int g = 0; g < 4; ++g) bias[g] = bs1[g * 512 + jb + ejj];
        float c = 0.f;

        // ---- prologue: fetch h0[0] into regs (needs L0 flag >= 1)
        uint32_t vb[8];
        if (wave == 0) poll_flags(ownF, 0u, crossF, 1u, lane);
        __syncthreads();
#pragma unroll
        for (int i = 0; i < 8; ++i) vb[i] = ald(h0i + i * 256 + tid);

        for (int t = 0; t < T_; ++t) {
            // ---- loop top: stage h0[t] into bl1 from prefetched regs
#pragma unroll
            for (int i = 0; i < 8; ++i) {
                const int u = i * 256 + tid;
                *(uint32_t*)&bl1[u >> 8][(u & 255) * 2] = vb[i];
            }
            // own peers done with t-1; L0 >= t+2 so h0[t+1] is published
            if (wave == 0)
                poll_flags(ownF, (uint32_t)t, crossF,
                           (uint32_t)(t + 2 < T_ ? t + 2 : T_), lane);
            __syncthreads();                       // barA: bl1 ready + poll done
            // ---- issue h1[t-1] reads + prefetch h0[t+1]; overlap with ih-MFMAs
            uint32_t va[8];
            {
                const uint32_t* hb = h1i + (size_t)((t + 1) & 1) * 2048;
#pragma unroll
                for (int i = 0; i < 8; ++i) va[i] = ald(hb + i * 256 + tid);
                const uint32_t* gb = h0i + (size_t)((t + 1) & 7) * 2048;
#pragma unroll
                for (int i = 0; i < 8; ++i) vb[i] = ald(gb + i * 256 + tid);
            }
            floatx4 acc[4] = {};
            {
                const f16* br1 = &bl1[hrow][wave * 128 + quad * 8];
#pragma unroll
                for (int kk = 0; kk < 4; ++kk) {
                    const half8 bv = *(const half8*)(br1 + kk * 32);
#pragma unroll
                    for (int gt = 0; gt < 4; ++gt)
                        acc[gt] = __builtin_amdgcn_mfma_f32_16x16x32_f16(
                            ai[gt][kk], bv, acc[gt], 0, 0, 0);
                }
            }
            __builtin_amdgcn_sched_barrier(0);     // keep bl0 writes (vmcnt wait) after ih-MFMAs
            // ---- stage h1[t-1] into bl0 (waits on va loads)
#pragma unroll
            for (int i = 0; i < 8; ++i) {
                const int u = i * 256 + tid;
                *(uint32_t*)&bl0[u >> 8][(u & 255) * 2] = va[i];
            }
            __syncthreads();                       // barB: bl0 ready
            {
                const f16* br0 = &bl0[hrow][wave * 128 + quad * 8];
#pragma unroll
                for (int kk = 0; kk < 4; ++kk) {
                    const half8 bv = *(const half8*)(br0 + kk * 32);
#pragma unroll
                    for (int gt = 0; gt < 4; ++gt)
                        acc[gt] = __builtin_amdgcn_mfma_f32_16x16x32_f16(
                            ah[gt][kk], bv, acc[gt], 0, 0, 0);
                }
            }
            if (lm < 8)
#pragma unroll
                for (int gt = 0; gt < 4; ++gt)
#pragma unroll
                    for (int r = 0; r < 4; ++r)
                        glp[wave][gt][quad * 4 + r][lm] = acc[gt][r];
            __syncthreads();                       // barC: glp ready
            if (tid < 128) {
                float gi = bias[0], gf = bias[1], gg = bias[2], go = bias[3];
#pragma unroll
                for (int w = 0; w < 4; ++w) {
                    gi += glp[w][0][ejj][eb]; gf += glp[w][1][ejj][eb];
                    gg += glp[w][2][ejj][eb]; go += glp[w][3][ejj][eb];
                }
                const float hn = lstm_cell(gi, gf, gg, go, c);
                const float ho = __shfl_xor(hn, 1);
                if (!(ejj & 1)) {
                    union { f16 h[2]; uint32_t u; } pk;
                    pk.h[0] = (f16)hn; pk.h[1] = (f16)ho;
                    ast(h1i + (size_t)(t & 1) * 2048 + (eb * H_ + jb + ejj) / 2, pk.u);
                }
                if (t == T_ - 1)
                    dout[(size_t)(b0 + eb) * H_ + jb + ejj] = hn;
            }
            __syncthreads();                       // barD: drains h stores
            if (tid == 0) ast(ownF + mem * 16, (uint32_t)(t + 1));
        }
    }
}

// ------------------------------------------------------------ launcher ------
extern "C" void kernel_launch(void* const* d_in, const int* in_sizes, int n_in,
                              void* d_out, int out_size, void* d_ws, size_t ws_size,
                              hipStream_t stream) {
    const float* x    = (const float*)d_in[0];
    const float* Wih0 = (const float*)d_in[1];
    const float* Whh0 = (const float*)d_in[2];
    const float* bih0 = (const float*)d_in[3];
    const float* bhh0 = (const float*)d_in[4];
    const float* mih0 = (const float*)d_in[5];
    const float* mhh0 = (const float*)d_in[6];
    const float* Wih1 = (const float*)d_in[7];
    const float* Whh1 = (const float*)d_in[8];
    const float* bih1 = (const float*)d_in[9];
    const float* bhh1 = (const float*)d_in[10];
    const float* mih1 = (const float*)d_in[11];
    const float* mhh1 = (const float*)d_in[12];

    char* ws = (char*)d_ws;
    uint32_t* flags = (uint32_t*)(ws + OFF_FLAGS);
    uint32_t* h0b   = (uint32_t*)(ws + OFF_H0B);
    uint32_t* h1b   = (uint32_t*)(ws + OFF_H1B);
    f16*   wih0 = (f16*)(ws + OFF_WIH0);
    f16*   whh0 = (f16*)(ws + OFF_WHH0);
    f16*   wih1 = (f16*)(ws + OFF_WIH1);
    f16*   whh1 = (f16*)(ws + OFF_WHH1);
    float* bs0  = (float*)(ws + OFF_B0);
    float* bs1  = (float*)(ws + OFF_B1);
    float* out  = (float*)d_out;

    // zero flags + h rings (ws is re-poisoned before every timed call)
    hipMemsetAsync(ws, 0, ZERO_BYTES, stream);

    k_maskw<<<512,  256, 0, stream>>>(Wih0, mih0, wih0, G_ * DIN_ / 4);
    k_maskw<<<1024, 256, 0, stream>>>(Whh0, mhh0, whh0, G_ * H_ / 4);
    k_maskw<<<1024, 256, 0, stream>>>(Wih1, mih1, wih1, G_ * H_ / 4);
    k_maskw<<<1024, 256, 0, stream>>>(Whh1, mhh1, whh1, G_ * H_ / 4);
    k_bias<<<8, 256, 0, stream>>>(bih0, bhh0, bs0);
    k_bias<<<8, 256, 0, stream>>>(bih1, bhh1, bs1);

    fused_rnn<<<512, 256, 0, stream>>>(x, wih0, whh0, bs0, wih1, whh1, bs1,
                                       out, h0b, h1b, flags);

    (void)in_sizes; (void)n_in; (void)out_size; (void)ws_size;
}